// Round 9
// baseline (64.803 us; speedup 1.0000x reference)
//
#include <hip/hip_runtime.h>

#define CIN   32
#define COUT  64
#define HH    64
#define WW    64
#define NB    4
#define TH    8              // rows per block
#define HR    (TH + 2)       // 10 staged rows
#define G     8              // input channels per LDS round
#define CPT   2              // output channels per thread (one co-pair per block)
#define ROWCI 72             // dwords per (row, ci): two 36-dword parity arrays
// parity array layout (36 dwords): [0]=left halo (col -1), [1..32]=cols, [33]=right halo (col 64)
// packed weights in ws: [copair][ci][36]: [A(co0) 9 | A(co1) 9 | C(co0) 9 | C(co1) 9], 16B-aligned

__global__ void pack_weights(const float* __restrict__ w,
                             const float* __restrict__ c,
                             float* __restrict__ ws)
{
    int idx = blockIdx.x * 256 + threadIdx.x;          // 0 .. 32*32*36-1
    if (idx >= 32 * 32 * 36) return;
    int pack = idx / 36, slot = idx - pack * 36;
    int copair = pack >> 5, ci = pack & 31;
    int set = slot / 18, rem = slot % 18, c2 = rem / 9, k = rem % 9;
    int co = copair * 2 + c2;
    const float* src = set ? c : w;
    ws[idx] = src[((size_t)co * CIN + ci) * 9 + k];
}

template<int S>
__device__ __forceinline__ void math_g(const float* __restrict__ sx,
                                       const float* __restrict__ wsv,  // laundered -> VMEM loads
                                       int copair, int lrow, int m, int cb, int g,
                                       float aeg[2][CPT], float cv[2][CPT])
{
    #pragma unroll 2
    for (int cl = 0; cl < G; ++cl) {
        const int ci = g + cl;
        // 15 taps: 5 window rows x (center b32 + side pair -> b64/read2)
        float tc[5], tl[5], tr[5];
        #pragma unroll
        for (int wr = 0; wr < 5; ++wr) {
            const int qc = (wr & 1) ^ 1 ^ S;              // compile-time array select
            const float* rowp = sx + (lrow + wr) * (G * ROWCI) + cl * ROWCI;
            tc[wr] = rowp[qc * 36 + 1 + m];
            const float* sp = rowp + (1 - qc) * 36 + m + cb;
            tl[wr] = sp[0];
            tr[wr] = sp[1];
        }

        // weights: 9 x global_load_dwordx4 (vector pipe, vmcnt; uniform addr = 1 line each)
        float w[36];
        const float4* wp = (const float4*)(wsv + ((size_t)(copair * CIN + ci) * 36));
        #pragma unroll
        for (int u = 0; u < 9; ++u)
            *(float4*)&w[4 * u] = wp[u];

        #pragma unroll
        for (int c = 0; c < CPT; ++c) {
            const float* wA = &w[c * 9];
            const float* wC = &w[18 + c * 9];
            #pragma unroll
            for (int p = 0; p < 2; ++p) {
                float r = 0.0f;
                #pragma unroll
                for (int k = 0; k < 9; ++k) {
                    const int wr = 2 * p + k / 3;
                    const int kj = k % 3;
                    const float t = (kj == 0) ? tl[wr] : ((kj == 1) ? tc[wr] : tr[wr]);
                    const float prod = t * wA[k];
                    // pixel parity == S -> step parity = S^(k&1); even: r=(r+t)*y, odd: r=(r+y)*t
                    r = ((k & 1) == S) ? fmaf(r, wA[k], prod) : fmaf(r, t, prod);
                    cv[p][c] = fmaf(t, wC[k], cv[p][c]);
                }
                aeg[p][c] += r;
            }
        }
    }
}

__global__ __launch_bounds__(256, 4)
void aeg_conv_kernel(const float* __restrict__ x,
                     const float* __restrict__ ws,
                     const float* __restrict__ conv_b,
                     float* __restrict__ out)
{
    __shared__ float sx[HR * G * ROWCI];          // 10*8*72*4 = 23040 B

    const int tid = threadIdx.x;
    const int i0  = blockIdx.x * TH;
    const int n   = blockIdx.y;
    const int copair = blockIdx.z;
    const int co0 = copair * CPT;

    const int s  = (tid >> 6) & 1;      // wave parity class (wave-uniform)
    const int rg = tid >> 7;            // row group (0,1)
    const int h  = (tid >> 5) & 1;      // half-wave -> row offset
    const int m  = tid & 31;

    const int rb_local = rg * 4 + h;            // local first pixel row: {0,1,4,5}; owns +0,+2
    const int rb  = i0 + rb_local;              // absolute first pixel row
    const int cb  = (rb & 1) ^ s;               // column LSB for this lane's class
    const int col = 2 * m + cb;                 // owned column (both pixel rows)

    const float* xn = x + (size_t)n * (CIN * HH * WW);

    // launder ws base into a VGPR so weight loads stay on the vector pipe (no s_load)
    const float* wsv = ws;
    asm volatile("" : "+v"(wsv));

    // ---- zero the halo-column slots (0 and 33) of every parity array, once ----
    for (int idx = tid; idx < HR * G * 2 * 2; idx += 256) {
        int arr  = idx >> 1;                    // 0..159
        int slot = (idx & 1) ? 33 : 0;
        sx[arr * 36 + slot] = 0.0f;
    }

    float aeg[2][CPT], cv[2][CPT];
    #pragma unroll
    for (int p = 0; p < 2; ++p)
        #pragma unroll
        for (int c = 0; c < CPT; ++c) { aeg[p][c] = 0.0f; cv[p][c] = 0.0f; }

    for (int g = 0; g < CIN; g += G) {
        __syncthreads();                // previous readers done (also covers halo init writes)
        // ---- stage HR rows x G ci, parity-split: 5 iters of float4 + 2 b64 writes ----
        #pragma unroll
        for (int it = 0; it < 5; ++it) {
            int idx  = it * 256 + tid;          // 0..1279
            int f4   = idx & 15;                // 16B chunk within row
            int pair = idx >> 4;                // r10*G + cl, 0..79
            int r10  = pair >> 3;
            int cl   = pair & 7;
            int gi   = i0 - 1 + r10;
            float4 v = make_float4(0.f, 0.f, 0.f, 0.f);
            if ((unsigned)gi < (unsigned)HH)
                v = *(const float4*)&xn[(g + cl) * (HH * WW) + gi * WW + 4 * f4];
            int rp   = gi & 1;                  // parity array holding even cols
            float* base = &sx[pair * ROWCI];
            // cols 4f4,4f4+2 -> array rp slots 1+2f4,2+2f4 ; cols 4f4+1,4f4+3 -> other array
            *(float2*)&base[rp * 36 + 1 + 2 * f4]       = make_float2(v.x, v.z);
            *(float2*)&base[(rp ^ 1) * 36 + 1 + 2 * f4] = make_float2(v.y, v.w);
        }
        __syncthreads();

        if (s == 0) math_g<0>(sx, wsv, copair, rb_local, m, cb, g, aeg, cv);
        else        math_g<1>(sx, wsv, copair, rb_local, m, cb, g, aeg, cv);
    }

    // ---- epilogue: sigmoid(aeg) * (conv + bias) ----
    #pragma unroll
    for (int p = 0; p < 2; ++p) {
        int i = rb + 2 * p;
        #pragma unroll
        for (int c = 0; c < CPT; ++c) {
            int co = co0 + c;
            float conv = cv[p][c] + conv_b[co];
            float sg = 1.0f / (1.0f + __expf(-aeg[p][c]));
            out[(((size_t)n * COUT + co) * HH + i) * WW + col] = sg * conv;
        }
    }
}

extern "C" void kernel_launch(void* const* d_in, const int* in_sizes, int n_in,
                              void* d_out, int out_size, void* d_ws, size_t ws_size,
                              hipStream_t stream) {
    const float* x      = (const float*)d_in[0];
    const float* weight = (const float*)d_in[1];
    const float* conv_w = (const float*)d_in[2];
    const float* conv_b = (const float*)d_in[3];
    float* out = (float*)d_out;
    float* wsf = (float*)d_ws;                  // needs 32*32*36*4 = 147456 B

    pack_weights<<<(32 * 32 * 36 + 255) / 256, 256, 0, stream>>>(weight, conv_w, wsf);

    dim3 grid(HH / TH, NB, COUT / CPT);   // 8 x 4 x 32 = 1024 blocks
    aeg_conv_kernel<<<grid, 256, 0, stream>>>(x, wsf, conv_b, out);
}

// Round 10
// 57.533 us; speedup vs baseline: 1.1264x; 1.1264x over previous
//
#include <hip/hip_runtime.h>

#define CIN   32
#define COUT  64
#define HH    64
#define WW    64
#define NB    4
#define TH    8              // rows per block
#define HR    (TH + 2)       // 10 staged rows
#define G     8              // input channels per LDS round
#define CPT   2              // output channels per thread (one co-pair per block)
#define ROWCI 72             // dwords per (row, ci): two 36-dword parity arrays
// parity array layout (36 dwords): [0]=left halo (col -1), [1..32]=cols, [33]=right halo (col 64)
// packed weights in ws: [copair][ci][36]: [A(co0) 9 | A(co1) 9 | C(co0) 9 | C(co1) 9]

__global__ void pack_weights(const float* __restrict__ w,
                             const float* __restrict__ c,
                             float* __restrict__ ws)
{
    int idx = blockIdx.x * 256 + threadIdx.x;          // 0 .. 32*32*36-1
    if (idx >= 32 * 32 * 36) return;
    int pack = idx / 36, slot = idx - pack * 36;
    int copair = pack >> 5, ci = pack & 31;
    int set = slot / 18, rem = slot % 18, c2 = rem / 9, k = rem % 9;
    int co = copair * 2 + c2;
    const float* src = set ? c : w;
    ws[idx] = src[((size_t)co * CIN + ci) * 9 + k];
}

// uniform address -> s_load_dwordx16 x2 + dwordx4 into SGPRs
__device__ __forceinline__ void loadw(float w[36], const float* __restrict__ p) {
    #pragma unroll
    for (int k = 0; k < 36; ++k) w[k] = p[k];
}

template<int S>
__device__ __forceinline__ void comp_ci(const float* __restrict__ sx,
                                        const float w[36],
                                        int lrow, int m, int cb, int cl,
                                        float aeg[2][CPT], float cv[2][CPT])
{
    // 15 taps: 5 window rows x (center b32 + side pair)
    float tc[5], tl[5], tr[5];
    #pragma unroll
    for (int wr = 0; wr < 5; ++wr) {
        const int qc = (wr & 1) ^ 1 ^ S;              // compile-time array select
        const float* rowp = sx + (lrow + wr) * (G * ROWCI) + cl * ROWCI;
        tc[wr] = rowp[qc * 36 + 1 + m];
        const float* sp = rowp + (1 - qc) * 36 + m + cb;
        tl[wr] = sp[0];
        tr[wr] = sp[1];
    }
    #pragma unroll
    for (int c = 0; c < CPT; ++c) {
        const float* wA = &w[c * 9];
        const float* wC = &w[18 + c * 9];
        #pragma unroll
        for (int p = 0; p < 2; ++p) {
            float r = 0.0f;
            #pragma unroll
            for (int k = 0; k < 9; ++k) {
                const int wr = 2 * p + k / 3;
                const int kj = k % 3;
                const float t = (kj == 0) ? tl[wr] : ((kj == 1) ? tc[wr] : tr[wr]);
                const float prod = t * wA[k];
                // pixel parity == S -> step parity = S^(k&1); even: r=(r+t)*y, odd: r=(r+y)*t
                r = ((k & 1) == S) ? fmaf(r, wA[k], prod) : fmaf(r, t, prod);
                cv[p][c] = fmaf(t, wC[k], cv[p][c]);
            }
            aeg[p][c] += r;
        }
    }
}

template<int S>
__device__ __forceinline__ void math_g(const float* __restrict__ sx,
                                       const float* __restrict__ wpk,  // &ws[copair*CIN*36]
                                       int lrow, int m, int cb, int g,
                                       float aeg[2][CPT], float cv[2][CPT])
{
    // double-buffered SGPR weight pipeline: issue s_load(next) before compute(cur)
    float wba[36], wbb[36];
    loadw(wba, wpk + (size_t)(g + 0) * 36);
    #pragma unroll 1
    for (int cl = 0; cl < G; cl += 2) {
        loadw(wbb, wpk + (size_t)(g + cl + 1) * 36);        // prefetch ci+1
        comp_ci<S>(sx, wba, lrow, m, cb, cl, aeg, cv);      // pure-register compute covers latency
        if (cl + 2 < G) loadw(wba, wpk + (size_t)(g + cl + 2) * 36);  // prefetch ci+2
        comp_ci<S>(sx, wbb, lrow, m, cb, cl + 1, aeg, cv);
    }
}

__global__ __launch_bounds__(256, 4)
void aeg_conv_kernel(const float* __restrict__ x,
                     const float* __restrict__ ws,
                     const float* __restrict__ conv_b,
                     float* __restrict__ out)
{
    __shared__ float sx[HR * G * ROWCI];          // 10*8*72*4 = 23040 B

    const int tid = threadIdx.x;
    const int i0  = blockIdx.x * TH;
    const int n   = blockIdx.y;
    const int copair = blockIdx.z;
    const int co0 = copair * CPT;

    const int s  = (tid >> 6) & 1;      // wave parity class (wave-uniform)
    const int rg = tid >> 7;            // row group (0,1)
    const int h  = (tid >> 5) & 1;      // half-wave -> row offset
    const int m  = tid & 31;

    const int rb_local = rg * 4 + h;            // local first pixel row: {0,1,4,5}; owns +0,+2
    const int rb  = i0 + rb_local;              // absolute first pixel row
    const int cb  = (rb & 1) ^ s;               // column LSB for this lane's class
    const int col = 2 * m + cb;                 // owned column (both pixel rows)

    const float* xn = x + (size_t)n * (CIN * HH * WW);
    const float* wpk = ws + (size_t)copair * CIN * 36;

    // ---- zero the halo-column slots (0 and 33) of every parity array, once ----
    for (int idx = tid; idx < HR * G * 2 * 2; idx += 256) {
        int arr  = idx >> 1;                    // 0..159
        int slot = (idx & 1) ? 33 : 0;
        sx[arr * 36 + slot] = 0.0f;
    }

    float aeg[2][CPT], cv[2][CPT];
    #pragma unroll
    for (int p = 0; p < 2; ++p)
        #pragma unroll
        for (int c = 0; c < CPT; ++c) { aeg[p][c] = 0.0f; cv[p][c] = 0.0f; }

    for (int g = 0; g < CIN; g += G) {
        __syncthreads();                // previous readers done (also covers halo init writes)
        // ---- stage HR rows x G ci, parity-split: 5 iters of float4 + 2 b64 writes ----
        #pragma unroll
        for (int it = 0; it < 5; ++it) {
            int idx  = it * 256 + tid;          // 0..1279
            int f4   = idx & 15;                // 16B chunk within row
            int pair = idx >> 4;                // r10*G + cl, 0..79
            int r10  = pair >> 3;
            int cl   = pair & 7;
            int gi   = i0 - 1 + r10;
            float4 v = make_float4(0.f, 0.f, 0.f, 0.f);
            if ((unsigned)gi < (unsigned)HH)
                v = *(const float4*)&xn[(g + cl) * (HH * WW) + gi * WW + 4 * f4];
            int rp   = gi & 1;                  // parity array holding even cols
            float* base = &sx[pair * ROWCI];
            // cols 4f4,4f4+2 -> array rp slots 1+2f4,2+2f4 ; cols 4f4+1,4f4+3 -> other array
            *(float2*)&base[rp * 36 + 1 + 2 * f4]       = make_float2(v.x, v.z);
            *(float2*)&base[(rp ^ 1) * 36 + 1 + 2 * f4] = make_float2(v.y, v.w);
        }
        __syncthreads();

        if (s == 0) math_g<0>(sx, wpk, rb_local, m, cb, g, aeg, cv);
        else        math_g<1>(sx, wpk, rb_local, m, cb, g, aeg, cv);
    }

    // ---- epilogue: sigmoid(aeg) * (conv + bias) ----
    #pragma unroll
    for (int p = 0; p < 2; ++p) {
        int i = rb + 2 * p;
        #pragma unroll
        for (int c = 0; c < CPT; ++c) {
            int co = co0 + c;
            float conv = cv[p][c] + conv_b[co];
            float sg = 1.0f / (1.0f + __expf(-aeg[p][c]));
            out[(((size_t)n * COUT + co) * HH + i) * WW + col] = sg * conv;
        }
    }
}

extern "C" void kernel_launch(void* const* d_in, const int* in_sizes, int n_in,
                              void* d_out, int out_size, void* d_ws, size_t ws_size,
                              hipStream_t stream) {
    const float* x      = (const float*)d_in[0];
    const float* weight = (const float*)d_in[1];
    const float* conv_w = (const float*)d_in[2];
    const float* conv_b = (const float*)d_in[3];
    float* out = (float*)d_out;
    float* wsf = (float*)d_ws;                  // needs 32*32*36*4 = 147456 B

    pack_weights<<<(32 * 32 * 36 + 255) / 256, 256, 0, stream>>>(weight, conv_w, wsf);

    dim3 grid(HH / TH, NB, COUT / CPT);   // 8 x 4 x 32 = 1024 blocks
    aeg_conv_kernel<<<grid, 256, 0, stream>>>(x, wsf, conv_b, out);
}

// Round 11
// 56.557 us; speedup vs baseline: 1.1458x; 1.0173x over previous
//
#include <hip/hip_runtime.h>

#define CIN   32
#define COUT  64
#define HH    64
#define WW    64
#define NB    4
#define TH    8              // rows per block
#define HR    (TH + 2)       // 10 staged rows
#define G     8              // input channels per LDS round
#define CPT   2              // output channels per thread (one co-pair per block)
#define ROWCI 72             // dwords per (row, ci): two 36-dword parity arrays
// parity array layout (36 dwords): [0]=left halo (col -1), [1..32]=cols, [33]=right halo (col 64)
// packed weights in ws: [copair][ci][36]: [A(co0) 9 | A(co1) 9 | C(co0) 9 | C(co1) 9]

__global__ void pack_weights(const float* __restrict__ w,
                             const float* __restrict__ c,
                             float* __restrict__ ws)
{
    int idx = blockIdx.x * 256 + threadIdx.x;          // 0 .. 32*32*36-1
    if (idx >= 32 * 32 * 36) return;
    int pack = idx / 36, slot = idx - pack * 36;
    int copair = pack >> 5, ci = pack & 31;
    int set = slot / 18, rem = slot % 18, c2 = rem / 9, k = rem % 9;
    int co = copair * 2 + c2;
    const float* src = set ? c : w;
    ws[idx] = src[((size_t)co * CIN + ci) * 9 + k];
}

// ---- staging split (T14): issue loads early, write to LDS late ----
__device__ __forceinline__ void load_tile(float4 pf[5], const float* __restrict__ xn,
                                          int i0, int g, int tid)
{
    #pragma unroll
    for (int it = 0; it < 5; ++it) {
        int idx  = it * 256 + tid;          // 0..1279
        int f4   = idx & 15;                // 16B chunk within row
        int pair = idx >> 4;                // r10*G + cl, 0..79
        int r10  = pair >> 3;
        int cl   = pair & 7;
        int gi   = i0 - 1 + r10;
        float4 v = make_float4(0.f, 0.f, 0.f, 0.f);
        if ((unsigned)gi < (unsigned)HH)
            v = *(const float4*)&xn[(g + cl) * (HH * WW) + gi * WW + 4 * f4];
        pf[it] = v;
    }
}

__device__ __forceinline__ void write_tile(const float4 pf[5], float* __restrict__ sx,
                                           int i0, int tid)
{
    #pragma unroll
    for (int it = 0; it < 5; ++it) {
        int idx  = it * 256 + tid;
        int f4   = idx & 15;
        int pair = idx >> 4;
        int r10  = pair >> 3;
        int gi   = i0 - 1 + r10;
        int rp   = gi & 1;                  // parity array holding even cols
        float4 v = pf[it];
        float* base = &sx[pair * ROWCI];
        // cols 4f4,4f4+2 -> array rp slots 1+2f4,2+2f4 ; cols 4f4+1,4f4+3 -> other array
        *(float2*)&base[rp * 36 + 1 + 2 * f4]       = make_float2(v.x, v.z);
        *(float2*)&base[(rp ^ 1) * 36 + 1 + 2 * f4] = make_float2(v.y, v.w);
    }
}

template<int S>
__device__ __forceinline__ void comp_ci(const float* __restrict__ sx,
                                        const float* __restrict__ sw,
                                        int lrow, int m, int cb, int cl,
                                        float aeg[2][CPT], float cv[2][CPT])
{
    // 15 taps: 5 window rows x (center b32 + side pair -> read2)
    float tc[5], tl[5], tr[5];
    #pragma unroll
    for (int wr = 0; wr < 5; ++wr) {
        const int qc = (wr & 1) ^ 1 ^ S;              // compile-time array select
        const float* rowp = sx + (lrow + wr) * (G * ROWCI) + cl * ROWCI;
        tc[wr] = rowp[qc * 36 + 1 + m];
        const float* sp = rowp + (1 - qc) * 36 + m + cb;
        tl[wr] = sp[0];
        tr[wr] = sp[1];
    }
    return; // placeholder removed below
}

template<int S>
__device__ __forceinline__ void comp_ci_full(const float* __restrict__ sx,
                                             const float* __restrict__ sw,
                                             int lrow, int m, int cb, int ci, int cl,
                                             float aeg[2][CPT], float cv[2][CPT])
{
    // 15 taps: 5 window rows x (center b32 + side pair)
    float tc[5], tl[5], tr[5];
    #pragma unroll
    for (int wr = 0; wr < 5; ++wr) {
        const int qc = (wr & 1) ^ 1 ^ S;              // compile-time array select
        const float* rowp = sx + (lrow + wr) * (G * ROWCI) + cl * ROWCI;
        tc[wr] = rowp[qc * 36 + 1 + m];
        const float* sp = rowp + (1 - qc) * 36 + m + cb;
        tl[wr] = sp[0];
        tr[wr] = sp[1];
    }

    // weights: 9 x ds_read_b128 broadcast (contiguous 36-dword pack, 16B-aligned)
    float w[36];
    const float* pw = sw + ci * 36;
    #pragma unroll
    for (int u = 0; u < 9; ++u)
        *(float4*)&w[4 * u] = *(const float4*)&pw[4 * u];

    #pragma unroll
    for (int c = 0; c < CPT; ++c) {
        const float* wA = &w[c * 9];
        const float* wC = &w[18 + c * 9];
        #pragma unroll
        for (int p = 0; p < 2; ++p) {
            float r = 0.0f;
            #pragma unroll
            for (int k = 0; k < 9; ++k) {
                const int wr = 2 * p + k / 3;
                const int kj = k % 3;
                const float t = (kj == 0) ? tl[wr] : ((kj == 1) ? tc[wr] : tr[wr]);
                const float prod = t * wA[k];
                // pixel parity == S -> step parity = S^(k&1); even: r=(r+t)*y, odd: r=(r+y)*t
                r = ((k & 1) == S) ? fmaf(r, wA[k], prod) : fmaf(r, t, prod);
                cv[p][c] = fmaf(t, wC[k], cv[p][c]);
            }
            aeg[p][c] += r;
        }
    }
}

template<int S>
__device__ __forceinline__ void math_g(const float* __restrict__ sx,
                                       const float* __restrict__ sw,
                                       int lrow, int m, int cb, int g,
                                       float aeg[2][CPT], float cv[2][CPT])
{
    #pragma unroll 4
    for (int cl = 0; cl < G; ++cl)
        comp_ci_full<S>(sx, sw, lrow, m, cb, g + cl, cl, aeg, cv);
}

__global__ __launch_bounds__(256, 4)
void aeg_conv_kernel(const float* __restrict__ x,
                     const float* __restrict__ ws,
                     const float* __restrict__ conv_b,
                     float* __restrict__ out)
{
    __shared__ float sx[HR * G * ROWCI];          // 10*8*72*4 = 23040 B
    __shared__ float sw[CIN * 36];                // 32*36*4   = 4608 B

    const int tid = threadIdx.x;
    const int i0  = blockIdx.x * TH;
    const int n   = blockIdx.y;
    const int copair = blockIdx.z;
    const int co0 = copair * CPT;

    const int s  = (tid >> 6) & 1;      // wave parity class (wave-uniform)
    const int rg = tid >> 7;            // row group (0,1)
    const int h  = (tid >> 5) & 1;      // half-wave -> row offset
    const int m  = tid & 31;

    const int rb_local = rg * 4 + h;            // local first pixel row: {0,1,4,5}; owns +0,+2
    const int rb  = i0 + rb_local;              // absolute first pixel row
    const int cb  = (rb & 1) ^ s;               // column LSB for this lane's class
    const int col = 2 * m + cb;                 // owned column (both pixel rows)

    const float* xn  = x + (size_t)n * (CIN * HH * WW);
    const float* wpk = ws + (size_t)copair * (CIN * 36);

    // ---- zero the halo-column slots (0 and 33) of every parity array, once ----
    for (int idx = tid; idx < HR * G * 2 * 2; idx += 256) {
        int arr  = idx >> 1;                    // 0..159
        int slot = (idx & 1) ? 33 : 0;
        sx[arr * 36 + slot] = 0.0f;
    }
    // ---- stage this block's packed weight slice into LDS (coalesced) ----
    for (int idx = tid; idx < CIN * 36; idx += 256)
        sw[idx] = wpk[idx];

    float aeg[2][CPT], cv[2][CPT];
    #pragma unroll
    for (int p = 0; p < 2; ++p)
        #pragma unroll
        for (int c = 0; c < CPT; ++c) { aeg[p][c] = 0.0f; cv[p][c] = 0.0f; }

    // T14 split: loads for round g issued one round ahead
    float4 pf[5];
    load_tile(pf, xn, i0, 0, tid);

    for (int g = 0; g < CIN; g += G) {
        __syncthreads();                // previous readers done (covers halo/sw init too)
        write_tile(pf, sx, i0, tid);    // vmcnt(0) here; loads issued ~1 compute-round ago
        __syncthreads();
        if (g + G < CIN)
            load_tile(pf, xn, i0, g + G, tid);   // issue next round's loads before compute
        if (s == 0) math_g<0>(sx, sw, rb_local, m, cb, g, aeg, cv);
        else        math_g<1>(sx, sw, rb_local, m, cb, g, aeg, cv);
    }

    // ---- epilogue: sigmoid(aeg) * (conv + bias) ----
    #pragma unroll
    for (int p = 0; p < 2; ++p) {
        int i = rb + 2 * p;
        #pragma unroll
        for (int c = 0; c < CPT; ++c) {
            int co = co0 + c;
            float conv = cv[p][c] + conv_b[co];
            float sg = 1.0f / (1.0f + __expf(-aeg[p][c]));
            out[(((size_t)n * COUT + co) * HH + i) * WW + col] = sg * conv;
        }
    }
}

extern "C" void kernel_launch(void* const* d_in, const int* in_sizes, int n_in,
                              void* d_out, int out_size, void* d_ws, size_t ws_size,
                              hipStream_t stream) {
    const float* x      = (const float*)d_in[0];
    const float* weight = (const float*)d_in[1];
    const float* conv_w = (const float*)d_in[2];
    const float* conv_b = (const float*)d_in[3];
    float* out = (float*)d_out;
    float* wsf = (float*)d_ws;                  // needs 32*32*36*4 = 147456 B

    pack_weights<<<(32 * 32 * 36 + 255) / 256, 256, 0, stream>>>(weight, conv_w, wsf);

    dim3 grid(HH / TH, NB, COUT / CPT);   // 8 x 4 x 32 = 1024 blocks
    aeg_conv_kernel<<<grid, 256, 0, stream>>>(x, wsf, conv_b, out);
}

// Round 12
// 37.022 us; speedup vs baseline: 1.7504x; 1.5276x over previous
//
#include <hip/hip_runtime.h>

#define CIN   32
#define COUT  64
#define HH    64
#define WW    64
#define NB    4
#define TH    8              // rows per block
#define HR    (TH + 2)       // 10 staged rows
#define G     8              // input channels per LDS round
#define CPT   2              // output channels per thread
#define ROWCI 72             // dwords per (row, ci): two 36-dword parity arrays
// parity array layout (36 dwords): [0]=left halo (col -1), [1..32]=cols, [33]=right halo (col 64)
// packed weight LDS: sw[ci][36] = [A(co0) 9 | A(co1) 9 | C(co0) 9 | C(co1) 9], 16B-aligned

template<int S>
__device__ __forceinline__ void math_g(const float* __restrict__ sx,
                                       const float* __restrict__ sw,
                                       int lrow, int m, int cb, int g,
                                       float aeg[2][CPT], float cv[2][CPT])
{
    #pragma unroll 2
    for (int cl = 0; cl < G; ++cl) {
        const int ci = g + cl;
        // 15 taps: 5 window rows x (center b32 + side pair -> ds_read2_b32)
        float tc[5], tl[5], tr[5];
        #pragma unroll
        for (int wr = 0; wr < 5; ++wr) {
            const int qc = (wr & 1) ^ 1 ^ S;              // compile-time array select
            const float* rowp = sx + (lrow + wr) * (G * ROWCI) + cl * ROWCI;
            tc[wr] = rowp[qc * 36 + 1 + m];
            const float* sp = rowp + (1 - qc) * 36 + m + cb;
            tl[wr] = sp[0];
            tr[wr] = sp[1];
        }

        // packed weights: 9 x ds_read_b128 broadcast (was 12 in the 39.5us anchor)
        float w[36];
        const float* pw = sw + ci * 36;
        #pragma unroll
        for (int u = 0; u < 9; ++u)
            *(float4*)&w[4 * u] = *(const float4*)&pw[4 * u];

        #pragma unroll
        for (int c = 0; c < CPT; ++c) {
            const float* wA = &w[c * 9];
            const float* wC = &w[18 + c * 9];
            #pragma unroll
            for (int p = 0; p < 2; ++p) {
                float r = 0.0f;
                #pragma unroll
                for (int k = 0; k < 9; ++k) {
                    const int wr = 2 * p + k / 3;
                    const int kj = k % 3;
                    const float t = (kj == 0) ? tl[wr] : ((kj == 1) ? tc[wr] : tr[wr]);
                    const float prod = t * wA[k];
                    // pixel parity == S -> step parity = S^(k&1); even: r=(r+t)*y, odd: r=(r+y)*t
                    r = ((k & 1) == S) ? fmaf(r, wA[k], prod) : fmaf(r, t, prod);
                    cv[p][c] = fmaf(t, wC[k], cv[p][c]);
                }
                aeg[p][c] += r;
            }
        }
    }
}

__global__ __launch_bounds__(256, 4)
void aeg_conv_kernel(const float* __restrict__ x,
                     const float* __restrict__ weight,
                     const float* __restrict__ conv_w,
                     const float* __restrict__ conv_b,
                     float* __restrict__ out)
{
    __shared__ float sx[HR * G * ROWCI];          // 10*8*72*4 = 23040 B
    __shared__ float sw[CIN * 36];                // 32*36*4   = 4608 B

    const int tid = threadIdx.x;
    const int i0  = blockIdx.x * TH;
    const int n   = blockIdx.y;
    const int co0 = blockIdx.z * CPT;

    const int s  = (tid >> 6) & 1;      // wave parity class (wave-uniform)
    const int rg = tid >> 7;            // row group (0,1)
    const int h  = (tid >> 5) & 1;      // half-wave -> row offset
    const int m  = tid & 31;

    const int rb_local = rg * 4 + h;            // local first pixel row: {0,1,4,5}; owns +0,+2
    const int rb  = i0 + rb_local;              // absolute first pixel row
    const int cb  = (rb & 1) ^ s;               // column LSB for this lane's class
    const int col = 2 * m + cb;                 // owned column (both pixel rows)

    const float* xn = x + (size_t)n * (CIN * HH * WW);

    // ---- zero the halo-column slots (0 and 33) of every parity array, once ----
    for (int idx = tid; idx < HR * G * 2 * 2; idx += 256) {
        int arr  = idx >> 1;                    // 0..159
        int slot = (idx & 1) ? 33 : 0;
        sx[arr * 36 + slot] = 0.0f;
    }

    // ---- stage packed weight slice into LDS: [ci][A0|A1|C0|C1] ----
    for (int idx = tid; idx < CIN * 36; idx += 256) {
        int ci = idx / 36, slot = idx - ci * 36;
        int set = slot / 18, rem = slot - set * 18;
        int c2 = rem / 9, k = rem - c2 * 9;
        const float* src = set ? conv_w : weight;
        sw[idx] = src[((size_t)(co0 + c2) * CIN + ci) * 9 + k];
    }

    float aeg[2][CPT], cv[2][CPT];
    #pragma unroll
    for (int p = 0; p < 2; ++p)
        #pragma unroll
        for (int c = 0; c < CPT; ++c) { aeg[p][c] = 0.0f; cv[p][c] = 0.0f; }

    for (int g = 0; g < CIN; g += G) {
        __syncthreads();                // previous readers done (also covers init writes)
        // ---- stage HR rows x G ci, parity-split: 5 iters of float4 + 4 b32 writes ----
        #pragma unroll
        for (int it = 0; it < 5; ++it) {
            int idx  = it * 256 + tid;          // 0..1279
            int f4   = idx & 15;                // 16B chunk within row
            int pair = idx >> 4;                // r10*G + cl, 0..79
            int r10  = pair >> 3;
            int cl   = pair & 7;
            int gi   = i0 - 1 + r10;
            float4 v = make_float4(0.f, 0.f, 0.f, 0.f);
            if ((unsigned)gi < (unsigned)HH)
                v = *(const float4*)&xn[(g + cl) * (HH * WW) + gi * WW + 4 * f4];
            int rp   = gi & 1;                  // parity array holding even cols
            float* base = &sx[pair * ROWCI];
            base[rp * 36 + 1 + 2 * f4]        = v.x;   // col 4f4
            base[rp * 36 + 2 + 2 * f4]        = v.z;   // col 4f4+2
            base[(rp ^ 1) * 36 + 1 + 2 * f4]  = v.y;   // col 4f4+1
            base[(rp ^ 1) * 36 + 2 + 2 * f4]  = v.w;   // col 4f4+3
        }
        __syncthreads();

        if (s == 0) math_g<0>(sx, sw, rb_local, m, cb, g, aeg, cv);
        else        math_g<1>(sx, sw, rb_local, m, cb, g, aeg, cv);
    }

    // ---- epilogue: sigmoid(aeg) * (conv + bias) ----
    #pragma unroll
    for (int p = 0; p < 2; ++p) {
        int i = rb + 2 * p;
        #pragma unroll
        for (int c = 0; c < CPT; ++c) {
            int co = co0 + c;
            float conv = cv[p][c] + conv_b[co];
            float sg = 1.0f / (1.0f + __expf(-aeg[p][c]));
            out[(((size_t)n * COUT + co) * HH + i) * WW + col] = sg * conv;
        }
    }
}

extern "C" void kernel_launch(void* const* d_in, const int* in_sizes, int n_in,
                              void* d_out, int out_size, void* d_ws, size_t ws_size,
                              hipStream_t stream) {
    const float* x      = (const float*)d_in[0];
    const float* weight = (const float*)d_in[1];
    const float* conv_w = (const float*)d_in[2];
    const float* conv_b = (const float*)d_in[3];
    float* out = (float*)d_out;

    dim3 grid(HH / TH, NB, COUT / CPT);   // 8 x 4 x 32 = 1024 blocks
    aeg_conv_kernel<<<grid, 256, 0, stream>>>(x, weight, conv_w, conv_b, out);
}